// Round 5
// baseline (264.665 us; speedup 1.0000x reference)
//
#include <hip/hip_runtime.h>

#define SSIM_H 512
#define SSIM_W 512
#define PLANES 96
#define TILE_W 64
#define TILE_H 32
#define GRID_X (SSIM_W / TILE_W)   // 8
#define GRID_Y (SSIM_H / TILE_H)   // 16
#define TOTAL_BLOCKS (GRID_X * GRID_Y * PLANES)  // 12288
#define N_TOTAL 25165824.0

typedef _Float16 half4v __attribute__((ext_vector_type(4)));
typedef _Float16 half8v __attribute__((ext_vector_type(8)));
typedef float float4v __attribute__((ext_vector_type(4)));

struct __align__(8) f2 { float x, y; };

// Gaussian tap k (0..10), sigma=1.5: exp(-(k-5)^2/4.5) / 3.759233
__device__ __forceinline__ float gwf(int k) {
  const float d = (float)(k - 5);
  return __expf(-d * d / 4.5f) * 0.26601171702936207f;
}

// Both conv passes as mfma_f32_16x16x32_f16 against a banded weight matrix.
// Weight fragment value = w[8q + j - (lane&15)]; serves as stage-1 B
// (B[k][n]=w[k-n]) and stage-2 A (A[i][kk]=w[kk-i]) with identical registers.
//
// Round-5 change (occupancy attack, part 2): R4 confirmed waves are the
// working lever (2x waves -> 1.18x; replay-from-L3 identical time -> still
// latency-bound, LDS again the binding resource at 4 blocks/CU).
//  * Tile 64x64 -> 64x32: H planes [4][64][44] = 22,528 B -> 7 blocks/CU
//    (28 waves/CU, 1.75x concurrency).
//  * Stage 1 drops 5 -> 3 row-groups: 3 serialized HBM round trips per
//    wave instead of 5 (-40% per-wave latency chain).
//  * Per-pixel math bit-identical to R4 (pure restructure). Partials
//    become float2 (12,288 blocks x 8B = 96 KB, same ws footprint);
//    finalize accumulates in double.
//
// H planes column-major [plane][col 64][row 44] f16. Stride 44 halves =
// 22 dwords, gcd(22,32)=2: 16 lanes of a quad-group hit 16 distinct even
// banks (same structure as R4's stride-42/38, measured 0 conflicts).
__global__ __launch_bounds__(256, 7)
void ssim_l1_kernel(const float* __restrict__ pred,
                    const float* __restrict__ targ,
                    f2* __restrict__ partials) {
  __shared__ _Float16 Hs[4][64][44];  // 22,528 B -> 7 blocks/CU
  __shared__ float red[2][4];

  const int tid = (int)threadIdx.x;
  const int wv = tid >> 6;    // wave: owns col-group wv in BOTH stages
  const int lane = tid & 63;
  const int q = lane >> 4;    // quad
  const int m = lane & 15;

  const int tr0 = (int)blockIdx.y * TILE_H;
  const int tc0 = (int)blockIdx.x * TILE_W;
  const size_t pbase = (size_t)blockIdx.z * (SSIM_H * SSIM_W);
  const float* __restrict__ xp = pred + pbase;
  const float* __restrict__ yp = targ + pbase;

  // Per-lane banded weight fragment.
  half8v wf;
#pragma unroll
  for (int j = 0; j < 8; ++j) {
    const int k = 8 * q + j - m;
    const float v = (k >= 0 && k <= 10) ? gwf(k) : 0.0f;
    wf[j] = (_Float16)v;
  }

  const int cw = tc0 + 16 * wv;      // wave's output col-group (global)
  const int cbase = cw - 5 + 8 * q;  // first of 8 raw cols for this lane
  const bool cfast = (cbase >= 0) && (cbase + 7 < SSIM_W);

  float l1 = 0.0f;

  // ---------------- Stage 1: horizontal conv -> Hs ----------------
  // H rows 0..47 generated (0..41 consumed); raw rows tr0-5 .. tr0+42.
#pragma unroll
  for (int rg = 0; rg < 3; ++rg) {
    const int grow = tr0 - 5 + rg * 16 + m;  // raw image row (H row rg*16+m)
    float xf[8], yf[8];
    if ((unsigned)grow < (unsigned)SSIM_H) {
      const float* __restrict__ xr = xp + (size_t)grow * SSIM_W;
      const float* __restrict__ yr = yp + (size_t)grow * SSIM_W;
      if (cfast) {
        float4 a0, a1, b0, b1;
        __builtin_memcpy(&a0, xr + cbase, 16);
        __builtin_memcpy(&a1, xr + cbase + 4, 16);
        __builtin_memcpy(&b0, yr + cbase, 16);
        __builtin_memcpy(&b1, yr + cbase + 4, 16);
        xf[0] = a0.x; xf[1] = a0.y; xf[2] = a0.z; xf[3] = a0.w;
        xf[4] = a1.x; xf[5] = a1.y; xf[6] = a1.z; xf[7] = a1.w;
        yf[0] = b0.x; yf[1] = b0.y; yf[2] = b0.z; yf[3] = b0.w;
        yf[4] = b1.x; yf[5] = b1.y; yf[6] = b1.z; yf[7] = b1.w;
      } else {
#pragma unroll
        for (int j = 0; j < 8; ++j) {
          const int c = cbase + j;
          const bool ok = (unsigned)c < (unsigned)SSIM_W;
          xf[j] = ok ? xr[c] : 0.0f;
          yf[j] = ok ? yr[c] : 0.0f;
        }
      }
    } else {
#pragma unroll
      for (int j = 0; j < 8; ++j) { xf[j] = 0.0f; yf[j] = 0.0f; }
    }

    // Exact fp32 L1 on core pixels, counted exactly once:
    // core rows hr in [5, 5+TILE_H), core cols k = 8q+j in [5,21).
    const int hr = rg * 16 + m;
    if (hr >= 5 && hr < 5 + TILE_H) {
#pragma unroll
      for (int j = 0; j < 8; ++j) {
        const int k = 8 * q + j;
        if (k >= 5 && k < 21) l1 += fabsf(xf[j] - yf[j]);
      }
    }

    // Build f16 A-frags for the 4 planes (x, y, x^2+y^2, xy).
    half8v ax, ay, axxyy, axy;
#pragma unroll
    for (int j = 0; j < 8; ++j) {
      const float x = xf[j], y = yf[j];
      ax[j]    = (_Float16)x;
      ay[j]    = (_Float16)y;
      axxyy[j] = (_Float16)(x * x + y * y);
      axy[j]   = (_Float16)(x * y);
    }
    const float4v z = {0.0f, 0.0f, 0.0f, 0.0f};
    float4v c0 = __builtin_amdgcn_mfma_f32_16x16x32_f16(ax,    wf, z, 0, 0, 0);
    float4v c1 = __builtin_amdgcn_mfma_f32_16x16x32_f16(ay,    wf, z, 0, 0, 0);
    float4v c2 = __builtin_amdgcn_mfma_f32_16x16x32_f16(axxyy, wf, z, 0, 0, 0);
    float4v c3 = __builtin_amdgcn_mfma_f32_16x16x32_f16(axy,   wf, z, 0, 0, 0);

    // C layout: col=lane&15, row=4q+reg (rows contiguous -> one b64/plane).
    // Skip rg=2,q=3 (rows 44-47): beyond the 44-row array, and never read.
    if (rg != 2 || q != 3) {
      const int hcol = 16 * wv + m;
      const int hrow = rg * 16 + 4 * q;
      half4v h;
      h[0] = (_Float16)c0[0]; h[1] = (_Float16)c0[1];
      h[2] = (_Float16)c0[2]; h[3] = (_Float16)c0[3];
      *(half4v*)&Hs[0][hcol][hrow] = h;
      h[0] = (_Float16)c1[0]; h[1] = (_Float16)c1[1];
      h[2] = (_Float16)c1[2]; h[3] = (_Float16)c1[3];
      *(half4v*)&Hs[1][hcol][hrow] = h;
      h[0] = (_Float16)c2[0]; h[1] = (_Float16)c2[1];
      h[2] = (_Float16)c2[2]; h[3] = (_Float16)c2[3];
      *(half4v*)&Hs[2][hcol][hrow] = h;
      h[0] = (_Float16)c3[0]; h[1] = (_Float16)c3[1];
      h[2] = (_Float16)c3[2]; h[3] = (_Float16)c3[3];
      *(half4v*)&Hs[3][hcol][hrow] = h;
    }
  }

  // Wave-private LDS dependency: wait for THIS wave's ds_writes only.
  // (Stage 2 reads only the column slab this wave wrote; no cross-wave
  // traffic, so no __syncthreads needed.) sched_barrier per rule #18.
  asm volatile("s_waitcnt lgkmcnt(0)" ::: "memory");
  __builtin_amdgcn_sched_barrier(0);

  // ---------------- Stage 2: vertical conv + SSIM (wave-private) ----------
  float ssim = 0.0f;
  {
    const int hcol = 16 * wv + m;  // B-frag col n = lane&15, own slab
    // Issue all 16 ds_read_b64 before any stage-2 MFMA.
    half8v bfr[2][4];
#pragma unroll
    for (int rb = 0; rb < 2; ++rb) {
      const int hrow = 16 * rb + 8 * q;  // window row base (band = rb)
      // hi half reads rows hrow+4..hrow+7; for rb=1,q=3 that is rows 44-47
      // whose taps w[kk-i] (kk>=28, i<=15) are identically zero -> clamp to
      // row 40 (valid, finite, zero-weighted: bit-exact result).
      const int hrow_hi = (hrow + 4 <= 40) ? hrow + 4 : 40;
#pragma unroll
      for (int p = 0; p < 4; ++p) {
        half4v lo = *(const half4v*)&Hs[p][hcol][hrow];
        half4v hi = *(const half4v*)&Hs[p][hcol][hrow_hi];
        bfr[rb][p] = __builtin_shufflevector(lo, hi, 0, 1, 2, 3, 4, 5, 6, 7);
      }
    }
    const float C1v = 1.0e-4f, C2v = 9.0e-4f;
#pragma unroll
    for (int rb = 0; rb < 2; ++rb) {
      const float4v z = {0.0f, 0.0f, 0.0f, 0.0f};
      float4v acc[4];
#pragma unroll
      for (int p = 0; p < 4; ++p)
        acc[p] = __builtin_amdgcn_mfma_f32_16x16x32_f16(wf, bfr[rb][p], z,
                                                        0, 0, 0);
#pragma unroll
      for (int r = 0; r < 4; ++r) {
        const float mu1 = acc[0][r], mu2 = acc[1][r];
        const float exxyy = acc[2][r], exy = acc[3][r];
        const float m11 = mu1 * mu1, m22 = mu2 * mu2, m12 = mu1 * mu2;
        const float num = (2.0f * m12 + C1v) * (2.0f * (exy - m12) + C2v);
        const float den = (m11 + m22 + C1v) *
                          ((exxyy - m11 - m22) + C2v);
        ssim += num / den;
      }
    }
  }

  // ---- Reduction: wave shuffle -> LDS -> block -> private partial slot ----
  float v0 = l1, v1 = ssim;
#pragma unroll
  for (int off = 32; off > 0; off >>= 1) {
    v0 += __shfl_down(v0, off, 64);
    v1 += __shfl_down(v1, off, 64);
  }
  if (lane == 0) { red[0][wv] = v0; red[1][wv] = v1; }
  __syncthreads();
  if (tid == 0) {
    f2 s;
    s.x = red[0][0] + red[0][1] + red[0][2] + red[0][3];
    s.y = red[1][0] + red[1][1] + red[1][2] + red[1][3];
    const int bid = ((int)blockIdx.z * GRID_Y + (int)blockIdx.y) * GRID_X +
                    (int)blockIdx.x;
    partials[bid] = s;
  }
}

__global__ __launch_bounds__(256)
void finalize_kernel(const f2* __restrict__ partials,
                     float* __restrict__ out) {
  __shared__ double red[2][4];
  const int tid = (int)threadIdx.x;
  double L = 0.0, S = 0.0;
  for (int i = tid; i < TOTAL_BLOCKS; i += 256) {
    const f2 v = partials[i];
    L += (double)v.x;
    S += (double)v.y;
  }
#pragma unroll
  for (int off = 32; off > 0; off >>= 1) {
    L += __shfl_down(L, off, 64);
    S += __shfl_down(S, off, 64);
  }
  const int lane = tid & 63, wid = tid >> 6;
  if (lane == 0) { red[0][wid] = L; red[1][wid] = S; }
  __syncthreads();
  if (tid == 0) {
    const double Ls = red[0][0] + red[0][1] + red[0][2] + red[0][3];
    const double Ss = red[1][0] + red[1][1] + red[1][2] + red[1][3];
    const double invN = 1.0 / N_TOTAL;
    out[0] = (float)(0.84 * (Ls * invN) + 0.16 * (1.0 - Ss * invN));
  }
}

extern "C" void kernel_launch(void* const* d_in, const int* in_sizes, int n_in,
                              void* d_out, int out_size, void* d_ws, size_t ws_size,
                              hipStream_t stream) {
  const float* pred = (const float*)d_in[0];
  const float* targ = (const float*)d_in[1];
  float* out = (float*)d_out;
  f2* partials = (f2*)d_ws;  // 12288 * 8 B = 96 KB

  dim3 grid(GRID_X, GRID_Y, PLANES);  // (8, 16, 96)
  ssim_l1_kernel<<<grid, 256, 0, stream>>>(pred, targ, partials);
  finalize_kernel<<<1, 256, 0, stream>>>(partials, out);
}

// Round 6
// 262.308 us; speedup vs baseline: 1.0090x; 1.0090x over previous
//
#include <hip/hip_runtime.h>

#define SSIM_H 512
#define SSIM_W 512
#define PLANES 96
#define TILE_W 64
#define TILE_H 32
#define GRID_X (SSIM_W / TILE_W)   // 8
#define GRID_Y (SSIM_H / TILE_H)   // 16
#define TOTAL_BLOCKS (GRID_X * GRID_Y * PLANES)  // 12288
#define N_TOTAL 25165824.0

// Raw staging geometry: rows tr0-5 .. tr0+38 (44), cols tc0-8 .. tc0+75
// (84 dwords, stride padded to 86), both images.
#define RAW_ROWS 44
#define RAW_STRIDE 86            // dwords; 86%32=22 -> <=4-way banks; rows 8B-aligned
#define RAW_CHUNKS (2 * RAW_ROWS * 21)  // 21 x 16B chunks per img-row = 1848
#define STG_FULL (RAW_CHUNKS / 256)     // 7
#define STG_TAIL (RAW_CHUNKS - STG_FULL * 256)  // 56

typedef _Float16 half4v __attribute__((ext_vector_type(4)));
typedef _Float16 half8v __attribute__((ext_vector_type(8)));
typedef float float4v __attribute__((ext_vector_type(4)));

struct __align__(8) f2 { float x, y; };

// Gaussian tap k (0..10), sigma=1.5: exp(-(k-5)^2/4.5) / 3.759233
__device__ __forceinline__ float gwf(int k) {
  const float d = (float)(k - 5);
  return __expf(-d * d / 4.5f) * 0.26601171702936207f;
}

// Round-6 change (chain attack): R4/R5 bracketed the concurrency lever --
// it is saturated (28 waves/CU no better than 16). The remaining stall is
// the per-wave serial chain: 3 serialized HBM round trips (compiler sinks
// loads to uses; R1-R3 proved register prefetch is un-winnable). Fix that
// the compiler cannot undo: stage the raw f32 tile into LDS via
//   {8 opaque asm global_load_dwordx4} -> ONE explicit vmcnt(0) drain ->
//   {ds_write} -> one __syncthreads
// = exactly one global round trip per wave; stage-1 then reads raw from
// LDS (~40cy lgkm chains). Per-pixel math bit-identical to R5 (staged
// values equal the directly-loaded values; same masking, same order).
__global__ __launch_bounds__(256, 3)
void ssim_l1_kernel(const float* __restrict__ pred,
                    const float* __restrict__ targ,
                    f2* __restrict__ partials) {
  __shared__ float Raw[2][RAW_ROWS][RAW_STRIDE];  // 30,272 B
  __shared__ _Float16 Hs[4][64][44];              // 22,528 B
  __shared__ float red[2][4];                     // total 52,832 -> 3/CU

  const int tid = (int)threadIdx.x;
  const int wv = tid >> 6;    // wave: owns col-group wv in BOTH stages
  const int lane = tid & 63;
  const int q = lane >> 4;    // quad
  const int m = lane & 15;

  const int tr0 = (int)blockIdx.y * TILE_H;
  const int tc0 = (int)blockIdx.x * TILE_W;
  const size_t pbase = (size_t)blockIdx.z * (SSIM_H * SSIM_W);
  const float* __restrict__ xp = pred + pbase;
  const float* __restrict__ yp = targ + pbase;

  // ---- Staging phase A: issue ALL global loads (opaque asm; un-sinkable).
  float4v stg[8];
  int doff[8];
#pragma unroll
  for (int k = 0; k < 8; ++k) {
    if (k < STG_FULL || tid < STG_TAIL) {
      const int c = k * 256 + tid;          // chunk id
      const int row = c / 42;               // 0..43
      const int rem = c - row * 42;
      const int img = rem / 21;             // 0..1
      const int pos = rem - img * 21;       // 0..20 (16B chunks)
      const int gr = min(max(tr0 - 5 + row, 0), SSIM_H - 1);
      const int gc = min(max(tc0 - 8 + 4 * pos, 0), SSIM_W - 4);
      const float* src = (img ? yp : xp) + ((size_t)gr << 9) + gc;
      asm volatile("global_load_dwordx4 %0, %1, off"
                   : "=v"(stg[k]) : "v"(src) : "memory");
      doff[k] = (img * RAW_ROWS + row) * RAW_STRIDE + 4 * pos;
    }
  }
  // ---- ONE drain for the whole tile (the only global round trip).
  asm volatile("s_waitcnt vmcnt(0)" ::: "memory");
  __builtin_amdgcn_sched_barrier(0);
  // ---- Staging phase B: LDS writes (b64 pairs; rows 8B-aligned).
#pragma unroll
  for (int k = 0; k < 8; ++k) {
    if (k < STG_FULL || tid < STG_TAIL) {
      float* d = &Raw[0][0][0] + doff[k];
      f2 lo, hi;
      lo.x = stg[k][0]; lo.y = stg[k][1];
      hi.x = stg[k][2]; hi.y = stg[k][3];
      *(f2*)d = lo;
      *(f2*)(d + 2) = hi;
    }
  }
  __syncthreads();

  // Per-lane banded weight fragment.
  half8v wf;
#pragma unroll
  for (int j = 0; j < 8; ++j) {
    const int k = 8 * q + j - m;
    const float v = (k >= 0 && k <= 10) ? gwf(k) : 0.0f;
    wf[j] = (_Float16)v;
  }

  const int cw = tc0 + 16 * wv;      // wave's output col-group (global)
  const int cbase = cw - 5 + 8 * q;  // first of 8 raw cols for this lane
  const int o = 16 * wv + 8 * q + 3; // dword offset of cbase within Raw row
  const bool xedge = (tc0 == 0) || (tc0 == SSIM_W - TILE_W);
  const bool yedge = (tr0 == 0) || (tr0 == SSIM_H - TILE_H);

  float l1 = 0.0f;

  // ---------------- Stage 1: horizontal conv -> Hs (LDS-fed) -------------
#pragma unroll
  for (int rg = 0; rg < 3; ++rg) {
    const int r = rg * 16 + m;          // H row / staged row index
    const int rs = r < 43 ? r : 43;     // rows 44-47: garbage, discarded
    const float* Rx = &Raw[0][rs][0];
    const float* Ry = &Raw[1][rs][0];
    // cbase is +3 dwords into the 16B-aligned staging -> b64 reads at o-1.
    f2 a0 = *(const f2*)(Rx + o - 1);
    f2 a1 = *(const f2*)(Rx + o + 1);
    f2 a2 = *(const f2*)(Rx + o + 3);
    f2 a3 = *(const f2*)(Rx + o + 5);
    float a4 = Rx[o + 7];
    f2 b0 = *(const f2*)(Ry + o - 1);
    f2 b1 = *(const f2*)(Ry + o + 1);
    f2 b2 = *(const f2*)(Ry + o + 3);
    f2 b3 = *(const f2*)(Ry + o + 5);
    float b4 = Ry[o + 7];
    float xf[8] = {a0.y, a1.x, a1.y, a2.x, a2.y, a3.x, a3.y, a4};
    float yf[8] = {b0.y, b1.x, b1.y, b2.x, b2.y, b3.x, b3.y, b4};

    if (yedge) {  // zero out-of-image rows (matches reference zero-pad)
      const bool okr = (unsigned)(tr0 - 5 + r) < (unsigned)SSIM_H;
#pragma unroll
      for (int j = 0; j < 8; ++j) {
        xf[j] = okr ? xf[j] : 0.0f;
        yf[j] = okr ? yf[j] : 0.0f;
      }
    }
    if (xedge) {  // zero out-of-image cols
#pragma unroll
      for (int j = 0; j < 8; ++j) {
        const bool ok = (unsigned)(cbase + j) < (unsigned)SSIM_W;
        xf[j] = ok ? xf[j] : 0.0f;
        yf[j] = ok ? yf[j] : 0.0f;
      }
    }

    // Exact fp32 L1 on core pixels, counted exactly once:
    // core rows hr in [5, 5+TILE_H), core cols k = 8q+j in [5,21).
    if (r >= 5 && r < 5 + TILE_H) {
#pragma unroll
      for (int j = 0; j < 8; ++j) {
        const int k = 8 * q + j;
        if (k >= 5 && k < 21) l1 += fabsf(xf[j] - yf[j]);
      }
    }

    // Build f16 A-frags for the 4 planes (x, y, x^2+y^2, xy).
    half8v ax, ay, axxyy, axy;
#pragma unroll
    for (int j = 0; j < 8; ++j) {
      const float x = xf[j], y = yf[j];
      ax[j]    = (_Float16)x;
      ay[j]    = (_Float16)y;
      axxyy[j] = (_Float16)(x * x + y * y);
      axy[j]   = (_Float16)(x * y);
    }
    const float4v z = {0.0f, 0.0f, 0.0f, 0.0f};
    float4v c0 = __builtin_amdgcn_mfma_f32_16x16x32_f16(ax,    wf, z, 0, 0, 0);
    float4v c1 = __builtin_amdgcn_mfma_f32_16x16x32_f16(ay,    wf, z, 0, 0, 0);
    float4v c2 = __builtin_amdgcn_mfma_f32_16x16x32_f16(axxyy, wf, z, 0, 0, 0);
    float4v c3 = __builtin_amdgcn_mfma_f32_16x16x32_f16(axy,   wf, z, 0, 0, 0);

    // C layout: col=lane&15, row=4q+reg (rows contiguous -> one b64/plane).
    // Skip rg=2,q=3 (rows 44-47): beyond the 44-row array, and never read.
    if (rg != 2 || q != 3) {
      const int hcol = 16 * wv + m;
      const int hrow = rg * 16 + 4 * q;
      half4v h;
      h[0] = (_Float16)c0[0]; h[1] = (_Float16)c0[1];
      h[2] = (_Float16)c0[2]; h[3] = (_Float16)c0[3];
      *(half4v*)&Hs[0][hcol][hrow] = h;
      h[0] = (_Float16)c1[0]; h[1] = (_Float16)c1[1];
      h[2] = (_Float16)c1[2]; h[3] = (_Float16)c1[3];
      *(half4v*)&Hs[1][hcol][hrow] = h;
      h[0] = (_Float16)c2[0]; h[1] = (_Float16)c2[1];
      h[2] = (_Float16)c2[2]; h[3] = (_Float16)c2[3];
      *(half4v*)&Hs[2][hcol][hrow] = h;
      h[0] = (_Float16)c3[0]; h[1] = (_Float16)c3[1];
      h[2] = (_Float16)c3[2]; h[3] = (_Float16)c3[3];
      *(half4v*)&Hs[3][hcol][hrow] = h;
    }
  }

  // Wave-private H dependency: DS ops from one wave complete in order, so
  // waiting lgkmcnt(0) covers this wave's H writes. (Stage 2 reads only
  // the column slab this wave wrote; no cross-wave H traffic.)
  asm volatile("s_waitcnt lgkmcnt(0)" ::: "memory");
  __builtin_amdgcn_sched_barrier(0);

  // ---------------- Stage 2: vertical conv + SSIM (wave-private) ----------
  float ssim = 0.0f;
  {
    const int hcol = 16 * wv + m;  // B-frag col n = lane&15, own slab
    half8v bfr[2][4];
#pragma unroll
    for (int rb = 0; rb < 2; ++rb) {
      const int hrow = 16 * rb + 8 * q;  // window row base (band = rb)
      // hi half reads rows hrow+4..hrow+7; for rb=1,q=3 that is rows 44-47
      // whose taps w[kk-i] (kk>=28, i<=15) are identically zero -> clamp to
      // row 40 (valid, finite, zero-weighted: bit-exact result).
      const int hrow_hi = (hrow + 4 <= 40) ? hrow + 4 : 40;
#pragma unroll
      for (int p = 0; p < 4; ++p) {
        half4v lo = *(const half4v*)&Hs[p][hcol][hrow];
        half4v hi = *(const half4v*)&Hs[p][hcol][hrow_hi];
        bfr[rb][p] = __builtin_shufflevector(lo, hi, 0, 1, 2, 3, 4, 5, 6, 7);
      }
    }
    const float C1v = 1.0e-4f, C2v = 9.0e-4f;
#pragma unroll
    for (int rb = 0; rb < 2; ++rb) {
      const float4v z = {0.0f, 0.0f, 0.0f, 0.0f};
      float4v acc[4];
#pragma unroll
      for (int p = 0; p < 4; ++p)
        acc[p] = __builtin_amdgcn_mfma_f32_16x16x32_f16(wf, bfr[rb][p], z,
                                                        0, 0, 0);
#pragma unroll
      for (int r = 0; r < 4; ++r) {
        const float mu1 = acc[0][r], mu2 = acc[1][r];
        const float exxyy = acc[2][r], exy = acc[3][r];
        const float m11 = mu1 * mu1, m22 = mu2 * mu2, m12 = mu1 * mu2;
        const float num = (2.0f * m12 + C1v) * (2.0f * (exy - m12) + C2v);
        const float den = (m11 + m22 + C1v) *
                          ((exxyy - m11 - m22) + C2v);
        ssim += num / den;
      }
    }
  }

  // ---- Reduction: wave shuffle -> LDS -> block -> private partial slot ----
  float v0 = l1, v1 = ssim;
#pragma unroll
  for (int off = 32; off > 0; off >>= 1) {
    v0 += __shfl_down(v0, off, 64);
    v1 += __shfl_down(v1, off, 64);
  }
  if (lane == 0) { red[0][wv] = v0; red[1][wv] = v1; }
  __syncthreads();
  if (tid == 0) {
    f2 s;
    s.x = red[0][0] + red[0][1] + red[0][2] + red[0][3];
    s.y = red[1][0] + red[1][1] + red[1][2] + red[1][3];
    const int bid = ((int)blockIdx.z * GRID_Y + (int)blockIdx.y) * GRID_X +
                    (int)blockIdx.x;
    partials[bid] = s;
  }
}

__global__ __launch_bounds__(256)
void finalize_kernel(const f2* __restrict__ partials,
                     float* __restrict__ out) {
  __shared__ double red[2][4];
  const int tid = (int)threadIdx.x;
  double L = 0.0, S = 0.0;
  for (int i = tid; i < TOTAL_BLOCKS; i += 256) {
    const f2 v = partials[i];
    L += (double)v.x;
    S += (double)v.y;
  }
#pragma unroll
  for (int off = 32; off > 0; off >>= 1) {
    L += __shfl_down(L, off, 64);
    S += __shfl_down(S, off, 64);
  }
  const int lane = tid & 63, wid = tid >> 6;
  if (lane == 0) { red[0][wid] = L; red[1][wid] = S; }
  __syncthreads();
  if (tid == 0) {
    const double Ls = red[0][0] + red[0][1] + red[0][2] + red[0][3];
    const double Ss = red[1][0] + red[1][1] + red[1][2] + red[1][3];
    const double invN = 1.0 / N_TOTAL;
    out[0] = (float)(0.84 * (Ls * invN) + 0.16 * (1.0 - Ss * invN));
  }
}

extern "C" void kernel_launch(void* const* d_in, const int* in_sizes, int n_in,
                              void* d_out, int out_size, void* d_ws, size_t ws_size,
                              hipStream_t stream) {
  const float* pred = (const float*)d_in[0];
  const float* targ = (const float*)d_in[1];
  float* out = (float*)d_out;
  f2* partials = (f2*)d_ws;  // 12288 * 8 B = 96 KB

  dim3 grid(GRID_X, GRID_Y, PLANES);  // (8, 16, 96)
  ssim_l1_kernel<<<grid, 256, 0, stream>>>(pred, targ, partials);
  finalize_kernel<<<1, 256, 0, stream>>>(partials, out);
}

// Round 7
// 251.109 us; speedup vs baseline: 1.0540x; 1.0446x over previous
//
#include <hip/hip_runtime.h>

#define SSIM_H 512
#define SSIM_W 512
#define PLANES 96
#define TILE 64
#define GRID_X (SSIM_W / TILE)
#define GRID_Y (SSIM_H / TILE)
#define TOTAL_BLOCKS (GRID_X * GRID_Y * PLANES)  // 6144
#define N_TOTAL 25165824.0

typedef _Float16 half4v __attribute__((ext_vector_type(4)));
typedef _Float16 half8v __attribute__((ext_vector_type(8)));
typedef float float4v __attribute__((ext_vector_type(4)));

struct __align__(16) d2 { double x, y; };

// Gaussian tap k (0..10), sigma=1.5: exp(-(k-5)^2/4.5) / 3.759233
__device__ __forceinline__ float gwf(int k) {
  const float d = (float)(k - 5);
  return __expf(-d * d / 4.5f) * 0.26601171702936207f;
}

// Both conv passes as mfma_f32_16x16x32_f16 against a banded weight matrix.
// Weight fragment value = w[8q + j - (lane&15)]; serves as stage-1 B
// (B[k][n]=w[k-n]) and stage-2 A (A[i][kk]=w[kk-i]) with identical registers.
//
// Round-7: REVERT to the R4 structure (best measured: 110 us). R4/R5/R6
// established that wall time tracks TOTAL VALU-issue cycles (475k/640k/754k
// per CU -> 110/117/131 us) and is insensitive to memory source (L3-fed
// replays identical) and to occupancy beyond ~16 waves/CU. So: keep R4's
// geometry and cut instructions:
//  * packed-f16 plane math: axxyy/axy via v_pk_mul/v_pk_fma on half8v
//    (replaces 24 f32 ops + 16 cvts per rg with 12 packed ops).
//  * 32-bit-offset global loads (SGPR base + voffset): kills per-lane
//    64-bit pointer arithmetic on the 20 loads.
//  * stage-2 ds_read_b128 for rb 0..2 (16B-aligned; start banks
//    (6m+4q)%32 cover all 16 even residues, 2 dwords/bank = balanced,
//    0 conflicts expected) -> kills ~48 register-pack movs. rb==3 keeps
//    the clamped two-b64 path (row-76..79 reads would hit garbage LDS:
//    NaN x 0 = NaN inside MFMA).
//
// H planes column-major [plane][col 64][row 76] f16. Stride 76 halves =
// 38 dwords == 6 mod 32 -> conflict-free (measured 0 conflicts in R4).
__global__ __launch_bounds__(256, 4)
void ssim_l1_kernel(const float* __restrict__ pred,
                    const float* __restrict__ targ,
                    double* __restrict__ partials) {
  __shared__ _Float16 Hs[4][64][76];  // 38,912 B -> 4 blocks/CU
  __shared__ float red[2][4];

  const int tid = (int)threadIdx.x;
  const int wv = tid >> 6;    // wave: owns col-group wv in BOTH stages
  const int lane = tid & 63;
  const int q = lane >> 4;    // quad
  const int m = lane & 15;

  const int tr0 = (int)blockIdx.y * TILE;
  const int tc0 = (int)blockIdx.x * TILE;
  const size_t pbase = (size_t)blockIdx.z * (SSIM_H * SSIM_W);
  const float* __restrict__ xp = pred + pbase;
  const float* __restrict__ yp = targ + pbase;

  // Per-lane banded weight fragment.
  half8v wf;
#pragma unroll
  for (int j = 0; j < 8; ++j) {
    const int k = 8 * q + j - m;
    const float v = (k >= 0 && k <= 10) ? gwf(k) : 0.0f;
    wf[j] = (_Float16)v;
  }

  const int cw = tc0 + 16 * wv;      // wave's output col-group (global)
  const int cbase = cw - 5 + 8 * q;  // first of 8 raw cols for this lane
  const bool cfast = (cbase >= 0) && (cbase + 7 < SSIM_W);

  float l1 = 0.0f;

  // ---------------- Stage 1: horizontal conv -> Hs ----------------
#pragma unroll
  for (int rg = 0; rg < 5; ++rg) {
    const int grow = tr0 - 5 + rg * 16 + m;  // raw image row (H row rg*16+m)
    float xf[8], yf[8];
    if ((unsigned)grow < (unsigned)SSIM_H) {
      if (cfast) {
        // Single 32-bit index; uniform SGPR base -> saddr-form loads.
        const unsigned off = ((unsigned)grow << 9) + (unsigned)cbase;
        float4 a0, a1, b0, b1;
        __builtin_memcpy(&a0, xp + off, 16);
        __builtin_memcpy(&a1, xp + off + 4, 16);
        __builtin_memcpy(&b0, yp + off, 16);
        __builtin_memcpy(&b1, yp + off + 4, 16);
        xf[0] = a0.x; xf[1] = a0.y; xf[2] = a0.z; xf[3] = a0.w;
        xf[4] = a1.x; xf[5] = a1.y; xf[6] = a1.z; xf[7] = a1.w;
        yf[0] = b0.x; yf[1] = b0.y; yf[2] = b0.z; yf[3] = b0.w;
        yf[4] = b1.x; yf[5] = b1.y; yf[6] = b1.z; yf[7] = b1.w;
      } else {
        const float* __restrict__ xr = xp + ((size_t)grow << 9);
        const float* __restrict__ yr = yp + ((size_t)grow << 9);
#pragma unroll
        for (int j = 0; j < 8; ++j) {
          const int c = cbase + j;
          const bool ok = (unsigned)c < (unsigned)SSIM_W;
          xf[j] = ok ? xr[c] : 0.0f;
          yf[j] = ok ? yr[c] : 0.0f;
        }
      }
    } else {
#pragma unroll
      for (int j = 0; j < 8; ++j) { xf[j] = 0.0f; yf[j] = 0.0f; }
    }

    // Exact fp32 L1 on core pixels, counted exactly once:
    // core rows hr in [5,69), core cols k = 8q+j in [5,21).
    const int hr = rg * 16 + m;
    if (hr >= 5 && hr < 69) {
#pragma unroll
      for (int j = 0; j < 8; ++j) {
        const int k = 8 * q + j;
        if (k >= 5 && k < 21) l1 += fabsf(xf[j] - yf[j]);
      }
    }

    // f16 A-frags: x, y converted; derived planes in PACKED f16 math
    // (v_pk_mul/v_pk_fma): axxyy = ax*ax + ay*ay, axy = ax*ay.
    half8v ax, ay;
#pragma unroll
    for (int j = 0; j < 8; ++j) {
      ax[j] = (_Float16)xf[j];
      ay[j] = (_Float16)yf[j];
    }
    half8v axxyy = ax * ax + ay * ay;
    half8v axy = ax * ay;

    const float4v z = {0.0f, 0.0f, 0.0f, 0.0f};
    float4v c0 = __builtin_amdgcn_mfma_f32_16x16x32_f16(ax,    wf, z, 0, 0, 0);
    float4v c1 = __builtin_amdgcn_mfma_f32_16x16x32_f16(ay,    wf, z, 0, 0, 0);
    float4v c2 = __builtin_amdgcn_mfma_f32_16x16x32_f16(axxyy, wf, z, 0, 0, 0);
    float4v c3 = __builtin_amdgcn_mfma_f32_16x16x32_f16(axy,   wf, z, 0, 0, 0);

    // C layout: col=lane&15, row=4q+reg (rows contiguous -> one b64/plane).
    // Skip rg=4,q=3 (rows 76-79): beyond the 76-row array, and never read.
    if (rg != 4 || q != 3) {
      const int hcol = 16 * wv + m;
      const int hrow = rg * 16 + 4 * q;
      half4v h;
      h[0] = (_Float16)c0[0]; h[1] = (_Float16)c0[1];
      h[2] = (_Float16)c0[2]; h[3] = (_Float16)c0[3];
      *(half4v*)&Hs[0][hcol][hrow] = h;
      h[0] = (_Float16)c1[0]; h[1] = (_Float16)c1[1];
      h[2] = (_Float16)c1[2]; h[3] = (_Float16)c1[3];
      *(half4v*)&Hs[1][hcol][hrow] = h;
      h[0] = (_Float16)c2[0]; h[1] = (_Float16)c2[1];
      h[2] = (_Float16)c2[2]; h[3] = (_Float16)c2[3];
      *(half4v*)&Hs[2][hcol][hrow] = h;
      h[0] = (_Float16)c3[0]; h[1] = (_Float16)c3[1];
      h[2] = (_Float16)c3[2]; h[3] = (_Float16)c3[3];
      *(half4v*)&Hs[3][hcol][hrow] = h;
    }
  }

  // Wave-private LDS dependency: wait for THIS wave's ds_writes only.
  // (Stage 2 reads only the column slab this wave wrote; no cross-wave
  // traffic, so no __syncthreads needed.) sched_barrier per rule #18.
  asm volatile("s_waitcnt lgkmcnt(0)" ::: "memory");
  __builtin_amdgcn_sched_barrier(0);

  // ---------------- Stage 2: vertical conv + SSIM (wave-private) ----------
  float ssim = 0.0f;
  {
    const int hcol = 16 * wv + m;  // B-frag col n = lane&15, own slab
    half8v bfr[4][4];
    // rb 0..2: rows 16rb+8q .. +7 are contiguous, 16B-aligned, max row 63
    // -> single ds_read_b128 per (rb,p). Start banks (6m+4q)%32 = all 16
    // even residues per q-group, 2 dwords/bank: balanced, no conflicts.
#pragma unroll
    for (int rb = 0; rb < 3; ++rb) {
      const int hrow = 16 * rb + 8 * q;
#pragma unroll
      for (int p = 0; p < 4; ++p)
        bfr[rb][p] = *(const half8v*)&Hs[p][hcol][hrow];
    }
    // rb == 3: q==3 would need rows 76-79 (beyond array; garbage LDS would
    // inject NaN x 0 into MFMA) -> clamped two-b64 path, zero-weight taps.
    {
      const int hrow = 48 + 8 * q;
      const int hrow_hi = (hrow + 4 <= 72) ? hrow + 4 : 72;
#pragma unroll
      for (int p = 0; p < 4; ++p) {
        half4v lo = *(const half4v*)&Hs[p][hcol][hrow];
        half4v hi = *(const half4v*)&Hs[p][hcol][hrow_hi];
        bfr[3][p] = __builtin_shufflevector(lo, hi, 0, 1, 2, 3, 4, 5, 6, 7);
      }
    }
    const float C1v = 1.0e-4f, C2v = 9.0e-4f;
#pragma unroll
    for (int rb = 0; rb < 4; ++rb) {
      const float4v z = {0.0f, 0.0f, 0.0f, 0.0f};
      float4v acc[4];
#pragma unroll
      for (int p = 0; p < 4; ++p)
        acc[p] = __builtin_amdgcn_mfma_f32_16x16x32_f16(wf, bfr[rb][p], z,
                                                        0, 0, 0);
#pragma unroll
      for (int r = 0; r < 4; ++r) {
        const float mu1 = acc[0][r], mu2 = acc[1][r];
        const float exxyy = acc[2][r], exy = acc[3][r];
        const float m11 = mu1 * mu1, m22 = mu2 * mu2, m12 = mu1 * mu2;
        const float num = (2.0f * m12 + C1v) * (2.0f * (exy - m12) + C2v);
        const float den = (m11 + m22 + C1v) *
                          ((exxyy - m11 - m22) + C2v);
        ssim += num / den;
      }
    }
  }

  // ---- Reduction: wave shuffle -> LDS -> block -> private partial slot ----
  float v0 = l1, v1 = ssim;
#pragma unroll
  for (int off = 32; off > 0; off >>= 1) {
    v0 += __shfl_down(v0, off, 64);
    v1 += __shfl_down(v1, off, 64);
  }
  if (lane == 0) { red[0][wv] = v0; red[1][wv] = v1; }
  __syncthreads();
  if (tid == 0) {
    d2 s;
    s.x = (double)red[0][0] + (double)red[0][1] +
          (double)red[0][2] + (double)red[0][3];
    s.y = (double)red[1][0] + (double)red[1][1] +
          (double)red[1][2] + (double)red[1][3];
    const int bid = ((int)blockIdx.z * GRID_Y + (int)blockIdx.y) * GRID_X +
                    (int)blockIdx.x;
    *(d2*)(partials + 2 * bid) = s;
  }
}

__global__ __launch_bounds__(256)
void finalize_kernel(const double* __restrict__ partials,
                     float* __restrict__ out) {
  __shared__ double red[2][4];
  const int tid = (int)threadIdx.x;
  double L = 0.0, S = 0.0;
  for (int i = tid; i < TOTAL_BLOCKS; i += 256) {
    const d2 v = *(const d2*)(partials + 2 * i);
    L += v.x;
    S += v.y;
  }
#pragma unroll
  for (int off = 32; off > 0; off >>= 1) {
    L += __shfl_down(L, off, 64);
    S += __shfl_down(S, off, 64);
  }
  const int lane = tid & 63, wid = tid >> 6;
  if (lane == 0) { red[0][wid] = L; red[1][wid] = S; }
  __syncthreads();
  if (tid == 0) {
    const double Ls = red[0][0] + red[0][1] + red[0][2] + red[0][3];
    const double Ss = red[1][0] + red[1][1] + red[1][2] + red[1][3];
    const double invN = 1.0 / N_TOTAL;
    out[0] = (float)(0.84 * (Ls * invN) + 0.16 * (1.0 - Ss * invN));
  }
}

extern "C" void kernel_launch(void* const* d_in, const int* in_sizes, int n_in,
                              void* d_out, int out_size, void* d_ws, size_t ws_size,
                              hipStream_t stream) {
  const float* pred = (const float*)d_in[0];
  const float* targ = (const float*)d_in[1];
  float* out = (float*)d_out;
  double* partials = (double*)d_ws;  // 6144 * 2 doubles = 96 KB

  dim3 grid(GRID_X, GRID_Y, PLANES);  // (8, 8, 96)
  ssim_l1_kernel<<<grid, 256, 0, stream>>>(pred, targ, partials);
  finalize_kernel<<<1, 256, 0, stream>>>(partials, out);
}